// Round 7
// baseline (945.019 us; speedup 1.0000x reference)
//
#include <hip/hip_runtime.h>
#include <hip/hip_bf16.h>
#include <type_traits>

// B=4, S=4096, H=1024, NH=8, HD=128, L=64 ; d = NH*HD = 1024
// M = B*S = 16384, K = N = 1024 for all five GEMMs.
#define GATE_ELEMS 16777216ull   // 16384 * 1024
#define W_ELEMS    1048576ull    // 1024 * 1024
#define NQ 128                   // scan chunks (32 steps each)

typedef float f32x4 __attribute__((ext_vector_type(4)));
typedef short s16x8 __attribute__((ext_vector_type(8)));
typedef unsigned short u16;

__device__ __forceinline__ u16 f2bf(float f) {
  union { float f; unsigned u; } v; v.f = f;
  unsigned r = v.u + 0x7fffu + ((v.u >> 16) & 1u);   // RNE round to bf16
  return (u16)(r >> 16);
}
__device__ __forceinline__ float bf2f(u16 u) {
  union { unsigned u; float f; } v; v.u = ((unsigned)u) << 16;
  return v.f;
}
__device__ __forceinline__ float sigmoidf_(float x) {
  return 1.0f / (1.0f + __expf(-x));
}
__device__ __forceinline__ float tanhf_(float x) {
  x = fminf(fmaxf(x, -15.f), 15.f);
  const float e = __expf(2.f * x);
  return (e - 1.f) / (e + 1.f);
}
__device__ __forceinline__ unsigned cvtpk(float lo, float hi) {
  unsigned r;
  asm("v_cvt_pk_bf16_f32 %0, %1, %2" : "=v"(r) : "v"(lo), "v"(hi));
  return r;
}
__device__ __forceinline__ void load_lds16(const u16* g, u16* l) {
  __builtin_amdgcn_global_load_lds(
      (const __attribute__((address_space(1))) unsigned int*)g,
      (__attribute__((address_space(3))) unsigned int*)l, 16, 0, 0);
}

// ---------------------------------------------------------------------------
// Weight fp32 -> bf16 convert (5 matrices, 8 elems/thread)
// ---------------------------------------------------------------------------
__global__ void cvt_w_kernel(const float* __restrict__ w0, const float* __restrict__ w1,
                             const float* __restrict__ w2, const float* __restrict__ w3,
                             const float* __restrict__ w4, u16* __restrict__ dst) {
  const float* src = (blockIdx.y == 0) ? w0 : (blockIdx.y == 1) ? w1
                   : (blockIdx.y == 2) ? w2 : (blockIdx.y == 3) ? w3 : w4;
  u16* d = dst + (size_t)blockIdx.y * W_ELEMS;
  const size_t i = ((size_t)blockIdx.x * 256 + threadIdx.x) * 8;
  const float4 a = *reinterpret_cast<const float4*>(src + i);
  const float4 b = *reinterpret_cast<const float4*>(src + i + 4);
  uint4 q;
  q.x = cvtpk(a.x, a.y); q.y = cvtpk(a.z, a.w);
  q.z = cvtpk(b.x, b.y); q.w = cvtpk(b.z, b.w);
  *reinterpret_cast<uint4*>(d + i) = q;
}

// ---------------------------------------------------------------------------
// Shared GEMM pieces: BM=BN=128, BK=64, 4 waves (2x2), dbuf 64 KiB LDS,
// XOR swizzle: 16-B slot ps = s ^ (row&7), one barrier per K-iter.
// LDS u16 layout per buf: [A 128x64][B 128x64], rows of 64 u16 (8 slots).
// ---------------------------------------------------------------------------
__device__ __forceinline__ void stage_bf16(const u16* __restrict__ M, int R0, int kt,
                                           u16* ldsbase, int tid) {
#pragma unroll
  for (int l = 0; l < 4; ++l) {
    const int T  = l * 256 + tid;          // 16-B slot index in the 16 KB tile
    const int r  = T >> 3;
    const int sl = (T & 7) ^ (r & 7);      // pre-swizzled global source
    load_lds16(M + (size_t)(R0 + r) * 1024 + kt + sl * 8,
               ldsbase + (T & ~63) * 8);   // linear LDS dest (HW adds lane*16B)
  }
}
__device__ __forceinline__ void a_issue(const float* __restrict__ A, int m0, int kt,
                                        int tid, float4 (&av)[8]) {
  const float* p = A + (size_t)(m0 + (tid >> 3)) * 1024 + kt + (tid & 7) * 8;
#pragma unroll
  for (int l = 0; l < 4; ++l) {
    av[2 * l]     = *reinterpret_cast<const float4*>(p + (size_t)l * 32 * 1024);
    av[2 * l + 1] = *reinterpret_cast<const float4*>(p + (size_t)l * 32 * 1024 + 4);
  }
}
__device__ __forceinline__ void a_write(u16* Abuf, int tid, const float4 (&av)[8]) {
  const int rb = tid >> 3, s = tid & 7;
#pragma unroll
  for (int l = 0; l < 4; ++l) {
    const int r  = rb + l * 32;
    const int ps = s ^ (r & 7);
    uint4 q;
    q.x = cvtpk(av[2 * l].x,     av[2 * l].y);
    q.y = cvtpk(av[2 * l].z,     av[2 * l].w);
    q.z = cvtpk(av[2 * l + 1].x, av[2 * l + 1].y);
    q.w = cvtpk(av[2 * l + 1].z, av[2 * l + 1].w);
    *reinterpret_cast<uint4*>(&Abuf[r * 64 + ps * 8]) = q;
  }
}

#define MFMA_BLOCK(Ab, Bb)                                                        \
  _Pragma("unroll")                                                               \
  for (int kk = 0; kk < 2; ++kk) {                                                \
    s16x8 a[4], b[4];                                                             \
    _Pragma("unroll")                                                             \
    for (int mf = 0; mf < 4; ++mf) {                                              \
      const int r  = wr * 64 + mf * 16 + frow;                                    \
      const int ps = (kk * 4 + kq) ^ (r & 7);                                     \
      a[mf] = *reinterpret_cast<const s16x8*>(&(Ab)[r * 64 + ps * 8]);            \
    }                                                                             \
    _Pragma("unroll")                                                             \
    for (int nf = 0; nf < 4; ++nf) {                                              \
      const int r  = wc * 64 + nf * 16 + frow;                                    \
      const int ps = (kk * 4 + kq) ^ (r & 7);                                     \
      b[nf] = *reinterpret_cast<const s16x8*>(&(Bb)[r * 64 + ps * 8]);            \
    }                                                                             \
    _Pragma("unroll")                                                             \
    for (int mf = 0; mf < 4; ++mf)                                                \
      _Pragma("unroll")                                                           \
      for (int nf = 0; nf < 4; ++nf)                                              \
        acc[mf][nf] = __builtin_amdgcn_mfma_f32_16x16x32_bf16(a[mf], b[nf],       \
                                                              acc[mf][nf], 0, 0, 0); \
  }

#define GEMM_PRE()                                                                \
  const int tid  = threadIdx.x;                                                   \
  const int lane = tid & 63;                                                      \
  const int wave = tid >> 6;                                                      \
  const int wr = wave >> 1, wc = wave & 1;                                        \
  const int frow = lane & 15, kq = lane >> 4;                                     \
  int bid = blockIdx.x;                                                           \
  bid = (bid & 7) * 128 + (bid >> 3);                                             \
  const int m0 = (bid >> 3) * 128;                                                \
  const int n0 = (bid & 7) * 128;                                                 \
  f32x4 acc[4][4];                                                                \
  _Pragma("unroll")                                                               \
  for (int i = 0; i < 4; ++i)                                                     \
    _Pragma("unroll")                                                             \
    for (int j = 0; j < 4; ++j)                                                   \
      acc[i][j] = (f32x4){0.f, 0.f, 0.f, 0.f};

#define GEMM_EPI(C, OT)                                                           \
  _Pragma("unroll")                                                               \
  for (int nf = 0; nf < 4; ++nf) {                                                \
    const int col = n0 + wc * 64 + nf * 16 + frow;                                \
    const float bv = bias[col];                                                   \
    _Pragma("unroll")                                                             \
    for (int mf = 0; mf < 4; ++mf) {                                              \
      const int rbase = m0 + wr * 64 + mf * 16 + kq * 4;                          \
      _Pragma("unroll")                                                           \
      for (int r = 0; r < 4; ++r) {                                               \
        const float v = acc[mf][nf][r] + bv;                                      \
        if constexpr (std::is_same<OT, float>::value)                             \
          (C)[(size_t)(rbase + r) * 1024 + col] = v;                              \
        else                                                                      \
          (C)[(size_t)(rbase + r) * 1024 + col] = f2bf(v);                        \
      }                                                                           \
    }                                                                             \
  }

// ---- gate GEMM: A fp32 (reg-staged cvt_pk), B bf16 (gload_lds), C bf16 ----
__global__ __launch_bounds__(256, 2)
void gemm_gate(const float* __restrict__ A, const u16* __restrict__ Bm,
               const float* __restrict__ bias, u16* __restrict__ C) {
  extern __shared__ u16 lds[];             // 2 bufs x (A 8192 + B 8192) u16
  GEMM_PRE();

  float4 av[8];
  a_issue(A, m0, 0, tid, av);
  stage_bf16(Bm, n0, 0, lds + 8192, tid);
  a_write(lds, tid, av);
  __syncthreads();

  int cur = 0;
#pragma unroll 2
  for (int t = 0; t < 16; ++t) {
    u16* nb = lds + (cur ^ 1) * 16384;
    if (t < 15) {
      a_issue(A, m0, (t + 1) * 64, tid, av);       // issue-early
      stage_bf16(Bm, n0, (t + 1) * 64, nb + 8192, tid);
    }
    const u16* Ab = lds + cur * 16384;
    const u16* Bb = Ab + 8192;
    MFMA_BLOCK(Ab, Bb);
    if (t < 15) a_write(nb, tid, av);              // write-late
    __syncthreads();
    cur ^= 1;
  }
  GEMM_EPI(C, u16);
}

// ---- final GEMM: A bf16 (gload_lds), B bf16 (gload_lds), C fp32 ----
__global__ __launch_bounds__(256, 2)
void gemm_out(const u16* __restrict__ A, const u16* __restrict__ Bm,
              const float* __restrict__ bias, float* __restrict__ C) {
  extern __shared__ u16 lds[];
  GEMM_PRE();

  stage_bf16(A,  m0, 0, lds,        tid);
  stage_bf16(Bm, n0, 0, lds + 8192, tid);
  __syncthreads();

  int cur = 0;
#pragma unroll 2
  for (int t = 0; t < 16; ++t) {
    if (t < 15) {
      u16* nb = lds + (cur ^ 1) * 16384;
      stage_bf16(A,  m0, (t + 1) * 64, nb,        tid);
      stage_bf16(Bm, n0, (t + 1) * 64, nb + 8192, tid);
    }
    const u16* Ab = lds + cur * 16384;
    const u16* Bb = Ab + 8192;
    MFMA_BLOCK(Ab, Bb);
    __syncthreads();
    cur ^= 1;
  }
  GEMM_EPI(C, float);
}

// ---------------------------------------------------------------------------
// Scan pass 1: chunks of 32 steps, 4 channels/thread, depth-8 prefetch.
// Summary layout [q][b][j], q in [0,128).
// ---------------------------------------------------------------------------
__global__ void scan_pass1(const u16* __restrict__ fx, const u16* __restrict__ ix,
                           const u16* __restrict__ zx,
                           float* __restrict__ P, float* __restrict__ cl) {
  const int t  = blockIdx.x * 256 + threadIdx.x;   // 0..131071
  const int jg = (t & 255) * 4;
  const int q  = (t >> 8) & 127;
  const int b  = t >> 15;
  const size_t base = ((size_t)(b * 4096 + q * 32)) * 1024 + jg;

  ushort4 pf[8], pi[8], pz[8];
#pragma unroll
  for (int d = 0; d < 8; ++d) {
    const size_t o = base + (size_t)d * 1024;
    pf[d] = *reinterpret_cast<const ushort4*>(fx + o);
    pi[d] = *reinterpret_cast<const ushort4*>(ix + o);
    pz[d] = *reinterpret_cast<const ushort4*>(zx + o);
  }
  float Pp[4] = {1.f, 1.f, 1.f, 1.f};
  float c[4]  = {0.f, 0.f, 0.f, 0.f};
#pragma unroll
  for (int s = 0; s < 32; ++s) {
    const ushort4 fv = pf[s & 7], iv = pi[s & 7], zv = pz[s & 7];
    if (s + 8 < 32) {
      const size_t o = base + (size_t)(s + 8) * 1024;
      pf[s & 7] = *reinterpret_cast<const ushort4*>(fx + o);
      pi[s & 7] = *reinterpret_cast<const ushort4*>(ix + o);
      pz[s & 7] = *reinterpret_cast<const ushort4*>(zx + o);
    }
    const u16* fp = (const u16*)&fv;
    const u16* ip = (const u16*)&iv;
    const u16* zp = (const u16*)&zv;
#pragma unroll
    for (int k = 0; k < 4; ++k) {
      const float f = sigmoidf_(bf2f(fp[k]) + 1.f);
      const float u = sigmoidf_(bf2f(ip[k])) * tanhf_(bf2f(zp[k]));
      Pp[k] *= f;
      c[k] = f * c[k] + u;
    }
  }
  const int sidx = q * 4096 + b * 1024 + jg;
  *reinterpret_cast<float4*>(P + sidx)  = make_float4(Pp[0], Pp[1], Pp[2], Pp[3]);
  *reinterpret_cast<float4*>(cl + sidx) = make_float4(c[0], c[1], c[2], c[3]);
}

// ---------------------------------------------------------------------------
// Scan pass 2: per-channel scan over 128 chunk summaries; carries + last_c.
// ---------------------------------------------------------------------------
__global__ void scan_pass2(const float* __restrict__ P, const float* __restrict__ cl,
                           const float* __restrict__ c0, float* __restrict__ cin,
                           float* __restrict__ lastc) {
  const int idx = blockIdx.x * 256 + threadIdx.x;  // 0..4095
  float carry = c0[idx];
#pragma unroll 8
  for (int q = 0; q < NQ; ++q) {
    const int s = q * 4096 + idx;
    cin[s] = carry;
    carry = fmaf(P[s], carry, cl[s]);
  }
  lastc[idx] = carry;
}

// ---------------------------------------------------------------------------
// Scan pass 3: replay with correct carry, compute h (bf16) + last_h.
// ---------------------------------------------------------------------------
__global__ void scan_pass3(const u16* __restrict__ fx, const u16* __restrict__ ix,
                           const u16* __restrict__ zx, const u16* __restrict__ ox,
                           const float* __restrict__ cin,
                           u16* __restrict__ h, float* __restrict__ lasth) {
  const int t  = blockIdx.x * 256 + threadIdx.x;
  const int jg = (t & 255) * 4;
  const int q  = (t >> 8) & 127;
  const int b  = t >> 15;
  const size_t base = ((size_t)(b * 4096 + q * 32)) * 1024 + jg;

  ushort4 pf[8], pi[8], pz[8], po[8];
#pragma unroll
  for (int d = 0; d < 8; ++d) {
    const size_t o = base + (size_t)d * 1024;
    pf[d] = *reinterpret_cast<const ushort4*>(fx + o);
    pi[d] = *reinterpret_cast<const ushort4*>(ix + o);
    pz[d] = *reinterpret_cast<const ushort4*>(zx + o);
    po[d] = *reinterpret_cast<const ushort4*>(ox + o);
  }
  const float4 ci = *reinterpret_cast<const float4*>(cin + q * 4096 + b * 1024 + jg);
  float c[4]  = {ci.x, ci.y, ci.z, ci.w};
  float hv[4] = {0.f, 0.f, 0.f, 0.f};
#pragma unroll
  for (int s = 0; s < 32; ++s) {
    const ushort4 fv = pf[s & 7], iv = pi[s & 7], zv = pz[s & 7], ov = po[s & 7];
    if (s + 8 < 32) {
      const size_t o = base + (size_t)(s + 8) * 1024;
      pf[s & 7] = *reinterpret_cast<const ushort4*>(fx + o);
      pi[s & 7] = *reinterpret_cast<const ushort4*>(ix + o);
      pz[s & 7] = *reinterpret_cast<const ushort4*>(zx + o);
      po[s & 7] = *reinterpret_cast<const ushort4*>(ox + o);
    }
    const u16* fp = (const u16*)&fv;
    const u16* ip = (const u16*)&iv;
    const u16* zp = (const u16*)&zv;
    const u16* op = (const u16*)&ov;
    ushort4 hw;
    u16* hp = (u16*)&hw;
#pragma unroll
    for (int k = 0; k < 4; ++k) {
      const float f = sigmoidf_(bf2f(fp[k]) + 1.f);
      const float u = sigmoidf_(bf2f(ip[k])) * tanhf_(bf2f(zp[k]));
      c[k] = f * c[k] + u;
      hv[k] = sigmoidf_(bf2f(op[k])) * tanhf_(c[k]);
      hp[k] = f2bf(hv[k]);
    }
    *reinterpret_cast<ushort4*>(h + base + (size_t)s * 1024) = hw;
  }
  if (q == NQ - 1)
    *reinterpret_cast<float4*>(lasth + b * 1024 + jg) =
        make_float4(hv[0], hv[1], hv[2], hv[3]);
}

// ---------------------------------------------------------------------------
extern "C" void kernel_launch(void* const* d_in, const int* in_sizes, int n_in,
                              void* d_out, int out_size, void* d_ws, size_t ws_size,
                              hipStream_t stream) {
  const float* xin[4]  = {(const float*)d_in[0], (const float*)d_in[1],
                          (const float*)d_in[2], (const float*)d_in[3]};
  const float* c0      = (const float*)d_in[4];
  const float* W[5]    = {(const float*)d_in[6], (const float*)d_in[8],
                          (const float*)d_in[10], (const float*)d_in[12],
                          (const float*)d_in[14]};
  const float* bias[5] = {(const float*)d_in[7], (const float*)d_in[9],
                          (const float*)d_in[11], (const float*)d_in[13],
                          (const float*)d_in[15]};
  float* out = (float*)d_out;

  (void)hipFuncSetAttribute((const void*)gemm_gate,
                            hipFuncAttributeMaxDynamicSharedMemorySize, 65536);
  (void)hipFuncSetAttribute((const void*)gemm_out,
                            hipFuncAttributeMaxDynamicSharedMemorySize, 65536);

  // Workspace (~144 MB): g1,g2,g3,h bf16 (4 x 32 MB), wbf (10 MB), summaries.
  u16* g1 = (u16*)d_ws;
  u16* g2 = g1 + GATE_ELEMS;
  u16* g3 = g2 + GATE_ELEMS;
  u16* h  = g3 + GATE_ELEMS;
  u16* wbf = h + GATE_ELEMS;
  float* Pbuf   = (float*)(wbf + 5 * W_ELEMS);
  float* clbuf  = Pbuf + NQ * 4096;
  float* cinbuf = clbuf + NQ * 4096;
  u16* g0 = (u16*)d_out;          // d_out scratch; consumed before final GEMM

  cvt_w_kernel<<<dim3(512, 5), 256, 0, stream>>>(W[0], W[1], W[2], W[3], W[4], wbf);

  u16* gp[4] = {g0, g1, g2, g3};
  for (int g = 0; g < 4; ++g)
    gemm_gate<<<1024, 256, 65536, stream>>>(
        xin[g], wbf + (size_t)g * W_ELEMS, bias[g], gp[g]);

  scan_pass1<<<512, 256, 0, stream>>>(g0, g1, g2, Pbuf, clbuf);
  scan_pass2<<<16, 256, 0, stream>>>(Pbuf, clbuf, c0, cinbuf, out + GATE_ELEMS);
  scan_pass3<<<512, 256, 0, stream>>>(g0, g1, g2, g3, cinbuf, h,
                                      out + GATE_ELEMS + 4096);

  gemm_out<<<1024, 256, 65536, stream>>>(h, wbf + 4 * W_ELEMS, bias[4], out);
}